// Round 3
// baseline (38.633 us; speedup 1.0000x reference)
//
#include <hip/hip_runtime.h>

// SuperResolve: A=4 frames, n=4, c=3, h=w=256, S=2 -> out (4,3,512,512) fp32
// One LR pixel per HALF-thread-pair: block = 128 pixels x 2 frame-halves.
// threads [0,128): pixel p, frames {0,1}; threads [128,256): pixel p, frames {2,3}.
// LDS-reduce the 16 accumulators, then half-0 finalizes + stores.
// Grid = 2048 blocks -> 8 blocks/CU -> 32 waves/CU (100% wave occupancy).

#define AF      4
#define NB      4
#define CH      3
#define H       256
#define W       256
#define SH      512
#define SW      512
#define HW      (H*W)
#define SHW     (SH*SW)
#define RADIUS  4.0f
// 0.25 (low-res displacement scaling) * 0.5*log2(e)  -> weight = exp2(-dist')
#define MSCALE  0.18033688011112042f
// clamp-hi: 20 * 0.5*log2(e)
#define CLHI    14.426950408889634f

__global__ __launch_bounds__(256, 8) void superresolve_kernel(
    const float* __restrict__ alts,     // [AF][NB][CH][H][W]
    const float* __restrict__ offsets,  // [AF][NB][2][H][W]
    const float* __restrict__ qs,       // [AF][NB][H][W]
    const float* __restrict__ o11,      // [NB][SH][SW]
    const float* __restrict__ o12,
    const float* __restrict__ o21,
    const float* __restrict__ o22,
    float* __restrict__ out)            // [NB][CH][SH][SW]
{
    __shared__ float red[128][17];      // +1 pad: conflict-free stride

    const int tid  = threadIdx.x;
    const int half = tid >> 7;          // 0: frames 0,1   1: frames 2,3
    const int lp   = tid & 127;

    // bijective XCD swizzle over 2048 blocks (2048 % 8 == 0)
    const int bid = blockIdx.x;
    const int swz = (bid & 7) * (2048 / 8) + (bid >> 3);
    const int P   = swz * 128 + lp;     // linear LR pixel id

    const int x0 = P & (W - 1);
    const int y0 = (P >> 8) & (H - 1);
    const int nn = P >> 16;

    // Per-subpixel o-matrices (float2, coalesced); fold 0.25*0.5*log2e in.
    const int obase = (nn * SH + 2 * y0) * SW + 2 * x0;
    const float2 v11a = *(const float2*)(o11 + obase);
    const float2 v11b = *(const float2*)(o11 + obase + SW);
    const float2 v12a = *(const float2*)(o12 + obase);
    const float2 v12b = *(const float2*)(o12 + obase + SW);
    const float2 v21a = *(const float2*)(o21 + obase);
    const float2 v21b = *(const float2*)(o21 + obase + SW);
    const float2 v22a = *(const float2*)(o22 + obase);
    const float2 v22b = *(const float2*)(o22 + obase + SW);

    float m11q[4], m12q[4], m22q[4];
    m11q[0] = MSCALE * v11a.x; m11q[1] = MSCALE * v11a.y;
    m11q[2] = MSCALE * v11b.x; m11q[3] = MSCALE * v11b.y;
    m12q[0] = MSCALE * (v12a.x + v21a.x); m12q[1] = MSCALE * (v12a.y + v21a.y);
    m12q[2] = MSCALE * (v12b.x + v21b.x); m12q[3] = MSCALE * (v12b.y + v21b.y);
    m22q[0] = MSCALE * v22a.x; m22q[1] = MSCALE * v22a.y;
    m22q[2] = MSCALE * v22b.x; m22q[3] = MSCALE * v22b.y;

    const float yf0 = (float)(2 * y0);
    const float xf0 = (float)(2 * x0);

    float sumw[4] = {0.f, 0.f, 0.f, 0.f};
    float acc0[4] = {0.f, 0.f, 0.f, 0.f};
    float acc1[4] = {0.f, 0.f, 0.f, 0.f};
    float acc2[4] = {0.f, 0.f, 0.f, 0.f};

    #pragma unroll
    for (int ai = 0; ai < 2; ++ai) {
        const int a = half * 2 + ai;
        const float* offb = offsets + (size_t)(a * NB + nn) * 2 * HW;
        const float* qb   = qs      + (size_t)(a * NB + nn) * HW;
        const float* altb = alts    + (size_t)(a * NB + nn) * CH * HW;
        #pragma unroll
        for (int k = 0; k < 9; ++k) {
            const int di = k / 3 - 1;
            const int dj = k % 3 - 1;
            const int rn = y0 + di;
            const int cn = x0 + dj;
            if (rn < 0 || rn >= H || cn < 0 || cn >= W) continue;  // inb: zero weight
            const int lidx = rn * W + cn;

            const float offr = offb[lidx];
            const float offc = offb[HW + lidx];
            const float qv   = qb[lidx];
            const float a0   = altb[lidx];
            const float a1   = altb[HW + lidx];
            const float a2   = altb[2 * HW + lidx];

            const float posr = (float)(2 * rn) + 2.0f * offr;
            const float posc = (float)(2 * cn) + 2.0f * offc;

            const float dy0 = posr - yf0;
            const float dy1 = dy0 - 1.0f;
            const float dx0 = posc - xf0;
            const float dx1 = dx0 - 1.0f;
            const bool vy0 = fabsf(dy0) <= RADIUS;
            const bool vy1 = fabsf(dy1) <= RADIUS;
            const bool vx0 = fabsf(dx0) <= RADIUS;
            const bool vx1 = fabsf(dx1) <= RADIUS;

            #pragma unroll
            for (int s = 0; s < 4; ++s) {
                const float dyS = (s & 2) ? dy1 : dy0;
                const float dxS = (s & 1) ? dx1 : dx0;
                const bool valid = ((s & 2) ? vy1 : vy0) & ((s & 1) ? vx1 : vx0);
                float dist = dxS * dxS * m11q[s] + dxS * dyS * m12q[s]
                           + dyS * dyS * m22q[s];
                dist = fminf(fmaxf(dist, 0.0f), CLHI);       // v_med3
                const float e = exp2f(-dist);                // v_exp_f32
                const float wgt = valid ? e * qv : 0.0f;
                sumw[s] += wgt;
                acc0[s] = fmaf(a0, wgt, acc0[s]);
                acc1[s] = fmaf(a1, wgt, acc1[s]);
                acc2[s] = fmaf(a2, wgt, acc2[s]);
            }
        }
    }

    // cross-half reduction: half 1 writes, half 0 accumulates + stores
    if (half) {
        #pragma unroll
        for (int s = 0; s < 4; ++s) {
            red[lp][s]      = sumw[s];
            red[lp][4 + s]  = acc0[s];
            red[lp][8 + s]  = acc1[s];
            red[lp][12 + s] = acc2[s];
        }
    }
    __syncthreads();
    if (!half) {
        #pragma unroll
        for (int s = 0; s < 4; ++s) {
            sumw[s] += red[lp][s];
            acc0[s] += red[lp][4 + s];
            acc1[s] += red[lp][8 + s];
            acc2[s] += red[lp][12 + s];
        }
        float inv[4];
        #pragma unroll
        for (int s = 0; s < 4; ++s) inv[s] = 1.0f / sumw[s];

        const size_t ob = (size_t)(nn * CH) * SHW + (size_t)(2 * y0) * SW + 2 * x0;
        *(float2*)(out + ob)              = make_float2(acc0[0]*inv[0], acc0[1]*inv[1]);
        *(float2*)(out + ob + SW)         = make_float2(acc0[2]*inv[2], acc0[3]*inv[3]);
        *(float2*)(out + ob + SHW)        = make_float2(acc1[0]*inv[0], acc1[1]*inv[1]);
        *(float2*)(out + ob + SHW + SW)   = make_float2(acc1[2]*inv[2], acc1[3]*inv[3]);
        *(float2*)(out + ob + 2*SHW)      = make_float2(acc2[0]*inv[0], acc2[1]*inv[1]);
        *(float2*)(out + ob + 2*SHW + SW) = make_float2(acc2[2]*inv[2], acc2[3]*inv[3]);
    }
}

extern "C" void kernel_launch(void* const* d_in, const int* in_sizes, int n_in,
                              void* d_out, int out_size, void* d_ws, size_t ws_size,
                              hipStream_t stream) {
    const float* alts    = (const float*)d_in[0];
    const float* offsets = (const float*)d_in[1];
    const float* qs      = (const float*)d_in[2];
    const float* o11     = (const float*)d_in[3];
    const float* o12     = (const float*)d_in[4];
    const float* o21     = (const float*)d_in[5];
    const float* o22     = (const float*)d_in[6];
    float* out = (float*)d_out;

    const int total_threads = NB * H * W * 2;   // 524,288 (2 frame-halves per pixel)
    const int block = 256;
    const int grid  = total_threads / block;    // 2048
    superresolve_kernel<<<grid, block, 0, stream>>>(alts, offsets, qs,
                                                    o11, o12, o21, o22, out);
}

// Round 4
// 34.022 us; speedup vs baseline: 1.1355x; 1.1355x over previous
//
#include <hip/hip_runtime.h>

// SuperResolve: A=4 frames, n=4, c=3, h=w=256, S=2 -> out (4,3,512,512) fp32
// One thread per LOW-RES pixel (nn,y0,x0); computes the 2x2 output quad.
// Inner quad math packed 2-wide over the sx pair -> v_pk_{fma,mul,max,min}_f32.
// R3 lesson: no waves-per-EU cap (forced VGPR=32 caused ~27MB scratch spills).

#define AF      4
#define NB      4
#define CH      3
#define H       256
#define W       256
#define SH      512
#define SW      512
#define HW      (H*W)
#define SHW     (SH*SW)
#define RADIUS  4.0f
// 0.25 (low-res displacement scaling) * 0.5*log2(e)  -> weight = exp2(-dist')
#define MSCALE  0.18033688011112042f
// clamp-hi: 20 * 0.5*log2(e)
#define CLHI    14.426950408889634f

typedef float v2f __attribute__((ext_vector_type(2)));

__global__ __launch_bounds__(256) void superresolve_kernel(
    const float* __restrict__ alts,     // [AF][NB][CH][H][W]
    const float* __restrict__ offsets,  // [AF][NB][2][H][W]
    const float* __restrict__ qs,       // [AF][NB][H][W]
    const float* __restrict__ o11,      // [NB][SH][SW]
    const float* __restrict__ o12,
    const float* __restrict__ o21,
    const float* __restrict__ o22,
    float* __restrict__ out)            // [NB][CH][SH][SW]
{
    // bijective XCD swizzle over 1024 blocks (1024 % 8 == 0)
    const int bid = blockIdx.x;
    const int swz = (bid & 7) * (1024 / 8) + (bid >> 3);
    const int idx = swz * 256 + threadIdx.x;

    const int x0 = idx & (W - 1);
    const int y0 = (idx >> 8) & (H - 1);
    const int nn = idx >> 16;

    // Per-subpixel o-matrices as sx-pairs (float2 loads, coalesced).
    // Index: [sy] over rows, vector lane over sx.
    const int obase = (nn * SH + 2 * y0) * SW + 2 * x0;
    const float2 v11a = *(const float2*)(o11 + obase);
    const float2 v11b = *(const float2*)(o11 + obase + SW);
    const float2 v12a = *(const float2*)(o12 + obase);
    const float2 v12b = *(const float2*)(o12 + obase + SW);
    const float2 v21a = *(const float2*)(o21 + obase);
    const float2 v21b = *(const float2*)(o21 + obase + SW);
    const float2 v22a = *(const float2*)(o22 + obase);
    const float2 v22b = *(const float2*)(o22 + obase + SW);

    v2f m11v[2], m12v[2], m22v[2];
    m11v[0] = (v2f){MSCALE * v11a.x, MSCALE * v11a.y};
    m11v[1] = (v2f){MSCALE * v11b.x, MSCALE * v11b.y};
    m12v[0] = (v2f){MSCALE * (v12a.x + v21a.x), MSCALE * (v12a.y + v21a.y)};
    m12v[1] = (v2f){MSCALE * (v12b.x + v21b.x), MSCALE * (v12b.y + v21b.y)};
    m22v[0] = (v2f){MSCALE * v22a.x, MSCALE * v22a.y};
    m22v[1] = (v2f){MSCALE * v22b.x, MSCALE * v22b.y};

    const float yf0 = (float)(2 * y0);
    const float xf0 = (float)(2 * x0);
    const float INF = __builtin_inff();

    v2f sumwv[2] = {(v2f){0.f,0.f}, (v2f){0.f,0.f}};
    v2f acc0v[2] = {(v2f){0.f,0.f}, (v2f){0.f,0.f}};
    v2f acc1v[2] = {(v2f){0.f,0.f}, (v2f){0.f,0.f}};
    v2f acc2v[2] = {(v2f){0.f,0.f}, (v2f){0.f,0.f}};

    #pragma unroll
    for (int a = 0; a < AF; ++a) {
        const float* offb = offsets + (size_t)(a * NB + nn) * 2 * HW;
        const float* qb   = qs      + (size_t)(a * NB + nn) * HW;
        const float* altb = alts    + (size_t)(a * NB + nn) * CH * HW;
        #pragma unroll
        for (int k = 0; k < 9; ++k) {
            const int di = k / 3 - 1;
            const int dj = k % 3 - 1;
            const int rn = y0 + di;
            const int cn = x0 + dj;
            if (rn < 0 || rn >= H || cn < 0 || cn >= W) continue;  // inb: zero weight
            const int lidx = rn * W + cn;

            const float offr = offb[lidx];
            const float offc = offb[HW + lidx];
            const float qv   = qb[lidx];
            const float a0   = altb[lidx];
            const float a1   = altb[HW + lidx];
            const float a2   = altb[2 * HW + lidx];

            const float posr = (float)(2 * rn) + 2.0f * offr;
            const float posc = (float)(2 * cn) + 2.0f * offc;

            const float dy0 = posr - yf0;       // sy = 0
            const float dy1 = dy0 - 1.0f;       // sy = 1
            const float dx0 = posc - xf0;       // sx = 0
            const float dx1 = dx0 - 1.0f;       // sx = 1
            const v2f  dxv  = (v2f){dx0, dx1};
            const bool vx0  = fabsf(dx0) <= RADIUS;
            const bool vx1  = fabsf(dx1) <= RADIUS;

            #pragma unroll
            for (int sy = 0; sy < 2; ++sy) {
                const float dy  = sy ? dy1 : dy0;
                const bool  vy  = fabsf(dy) <= RADIUS;
                const float dy2 = dy * dy;
                // dist = dx*(dx*m11 + dy*m12) + dy^2*m22   (packed over sx)
                v2f u  = dxv * m11v[sy] + dy * m12v[sy];
                v2f dv = dxv * u + dy2 * m22v[sy];
                dv = __builtin_elementwise_max(dv, (v2f){0.f, 0.f});
                dv = __builtin_elementwise_min(dv, (v2f){CLHI, CLHI});
                // exact zero weight for invalid neighbors: dist=+inf -> exp2 = 0
                const float f0 = (vy && vx0) ? dv.x : INF;
                const float f1 = (vy && vx1) ? dv.y : INF;
                const v2f ev = (v2f){exp2f(-f0), exp2f(-f1)};
                const v2f wv = ev * qv;
                sumwv[sy] += wv;
                acc0v[sy] += wv * a0;
                acc1v[sy] += wv * a1;
                acc2v[sy] += wv * a2;
            }
        }
    }

    v2f inv[2];
    #pragma unroll
    for (int sy = 0; sy < 2; ++sy)
        inv[sy] = (v2f){1.0f / sumwv[sy].x, 1.0f / sumwv[sy].y};

    const size_t ob = (size_t)(nn * CH) * SHW + (size_t)(2 * y0) * SW + 2 * x0;
    #pragma unroll
    for (int sy = 0; sy < 2; ++sy) {
        const v2f r0 = acc0v[sy] * inv[sy];
        const v2f r1 = acc1v[sy] * inv[sy];
        const v2f r2 = acc2v[sy] * inv[sy];
        *(float2*)(out + ob + (size_t)sy * SW)           = make_float2(r0.x, r0.y);
        *(float2*)(out + ob + (size_t)sy * SW + SHW)     = make_float2(r1.x, r1.y);
        *(float2*)(out + ob + (size_t)sy * SW + 2*SHW)   = make_float2(r2.x, r2.y);
    }
}

extern "C" void kernel_launch(void* const* d_in, const int* in_sizes, int n_in,
                              void* d_out, int out_size, void* d_ws, size_t ws_size,
                              hipStream_t stream) {
    const float* alts    = (const float*)d_in[0];
    const float* offsets = (const float*)d_in[1];
    const float* qs      = (const float*)d_in[2];
    const float* o11     = (const float*)d_in[3];
    const float* o12     = (const float*)d_in[4];
    const float* o21     = (const float*)d_in[5];
    const float* o22     = (const float*)d_in[6];
    float* out = (float*)d_out;

    const int total = NB * H * W;            // 262,144 threads (one per LR pixel)
    const int block = 256;
    const int grid  = total / block;         // 1024
    superresolve_kernel<<<grid, block, 0, stream>>>(alts, offsets, qs,
                                                    o11, o12, o21, o22, out);
}

// Round 5
// 31.659 us; speedup vs baseline: 1.2203x; 1.0747x over previous
//
#include <hip/hip_runtime.h>

// SuperResolve: A=4 frames, n=4, c=3, h=w=256, S=2 -> out (4,3,512,512) fp32
// One LR pixel per lane-PAIR within a wave: lane i (i<32) and lane i+32 handle
// the same pixel with frames {0,1} / {2,3}. Reduction = 16x shfl_xor(32) in
// registers -- no LDS, no barrier. 2048 blocks -> 8 blocks/CU -> 32 waves/CU.
// R3 lesson: no waves/EU launch-bounds cap (forced VGPR=32 -> 27MB spills).
// R4 lesson: 1024 blocks gave only 26% occupancy; latency-bound, need waves.

#define AF      4
#define NB      4
#define CH      3
#define H       256
#define W       256
#define SH      512
#define SW      512
#define HW      (H*W)
#define SHW     (SH*SW)
#define RADIUS  4.0f
// 0.25 (low-res displacement scaling) * 0.5*log2(e)  -> weight = exp2(-dist')
#define MSCALE  0.18033688011112042f
// clamp-hi: 20 * 0.5*log2(e)
#define CLHI    14.426950408889634f

typedef float v2f __attribute__((ext_vector_type(2)));

__global__ __launch_bounds__(256) void superresolve_kernel(
    const float* __restrict__ alts,     // [AF][NB][CH][H][W]
    const float* __restrict__ offsets,  // [AF][NB][2][H][W]
    const float* __restrict__ qs,       // [AF][NB][H][W]
    const float* __restrict__ o11,      // [NB][SH][SW]
    const float* __restrict__ o12,
    const float* __restrict__ o21,
    const float* __restrict__ o22,
    float* __restrict__ out)            // [NB][CH][SH][SW]
{
    const int tid   = threadIdx.x;
    const int lane  = tid & 63;
    const int wv    = tid >> 6;
    const int fhalf = lane >> 5;            // 0: frames {0,1}  1: frames {2,3}
    const int lp    = wv * 32 + (lane & 31);   // pixel index in block [0,128)

    // bijective XCD swizzle over 2048 blocks (2048 % 8 == 0)
    const int bid = blockIdx.x;
    const int swz = (bid & 7) * (2048 / 8) + (bid >> 3);
    const int P   = swz * 128 + lp;         // linear LR pixel id

    const int x0 = P & (W - 1);
    const int y0 = (P >> 8) & (H - 1);
    const int nn = P >> 16;

    // Per-subpixel o-matrices as sx-pairs (float2 loads; both halves read the
    // same addresses -> same cache lines).
    const int obase = (nn * SH + 2 * y0) * SW + 2 * x0;
    const float2 v11a = *(const float2*)(o11 + obase);
    const float2 v11b = *(const float2*)(o11 + obase + SW);
    const float2 v12a = *(const float2*)(o12 + obase);
    const float2 v12b = *(const float2*)(o12 + obase + SW);
    const float2 v21a = *(const float2*)(o21 + obase);
    const float2 v21b = *(const float2*)(o21 + obase + SW);
    const float2 v22a = *(const float2*)(o22 + obase);
    const float2 v22b = *(const float2*)(o22 + obase + SW);

    v2f m11v[2], m12v[2], m22v[2];
    m11v[0] = (v2f){MSCALE * v11a.x, MSCALE * v11a.y};
    m11v[1] = (v2f){MSCALE * v11b.x, MSCALE * v11b.y};
    m12v[0] = (v2f){MSCALE * (v12a.x + v21a.x), MSCALE * (v12a.y + v21a.y)};
    m12v[1] = (v2f){MSCALE * (v12b.x + v21b.x), MSCALE * (v12b.y + v21b.y)};
    m22v[0] = (v2f){MSCALE * v22a.x, MSCALE * v22a.y};
    m22v[1] = (v2f){MSCALE * v22b.x, MSCALE * v22b.y};

    const float yf0 = (float)(2 * y0);
    const float xf0 = (float)(2 * x0);
    const float INF = __builtin_inff();

    v2f sumwv[2] = {(v2f){0.f,0.f}, (v2f){0.f,0.f}};
    v2f acc0v[2] = {(v2f){0.f,0.f}, (v2f){0.f,0.f}};
    v2f acc1v[2] = {(v2f){0.f,0.f}, (v2f){0.f,0.f}};
    v2f acc2v[2] = {(v2f){0.f,0.f}, (v2f){0.f,0.f}};

    #pragma unroll
    for (int ai = 0; ai < 2; ++ai) {
        const int a = fhalf * 2 + ai;
        const float* offb = offsets + (size_t)(a * NB + nn) * 2 * HW;
        const float* qb   = qs      + (size_t)(a * NB + nn) * HW;
        const float* altb = alts    + (size_t)(a * NB + nn) * CH * HW;
        #pragma unroll
        for (int k = 0; k < 9; ++k) {
            const int di = k / 3 - 1;
            const int dj = k % 3 - 1;
            const int rn = y0 + di;
            const int cn = x0 + dj;
            if (rn < 0 || rn >= H || cn < 0 || cn >= W) continue;  // inb: zero weight
            const int lidx = rn * W + cn;

            const float offr = offb[lidx];
            const float offc = offb[HW + lidx];
            const float qv   = qb[lidx];
            const float a0   = altb[lidx];
            const float a1   = altb[HW + lidx];
            const float a2   = altb[2 * HW + lidx];

            const float posr = (float)(2 * rn) + 2.0f * offr;
            const float posc = (float)(2 * cn) + 2.0f * offc;

            const float dy0 = posr - yf0;       // sy = 0
            const float dy1 = dy0 - 1.0f;       // sy = 1
            const float dx0 = posc - xf0;       // sx = 0
            const float dx1 = dx0 - 1.0f;       // sx = 1
            const v2f  dxv  = (v2f){dx0, dx1};
            const bool vx0  = fabsf(dx0) <= RADIUS;
            const bool vx1  = fabsf(dx1) <= RADIUS;

            #pragma unroll
            for (int sy = 0; sy < 2; ++sy) {
                const float dy  = sy ? dy1 : dy0;
                const bool  vy  = fabsf(dy) <= RADIUS;
                const float dy2 = dy * dy;
                // dist = dx*(dx*m11 + dy*m12) + dy^2*m22   (packed over sx)
                v2f u  = dxv * m11v[sy] + dy * m12v[sy];
                v2f dv = dxv * u + dy2 * m22v[sy];
                dv = __builtin_elementwise_max(dv, (v2f){0.f, 0.f});
                dv = __builtin_elementwise_min(dv, (v2f){CLHI, CLHI});
                // exact zero weight for invalid neighbors: dist=+inf -> exp2 = 0
                const float f0 = (vy && vx0) ? dv.x : INF;
                const float f1 = (vy && vx1) ? dv.y : INF;
                const v2f ev = (v2f){exp2f(-f0), exp2f(-f1)};
                const v2f wv2 = ev * qv;
                sumwv[sy] += wv2;
                acc0v[sy] += wv2 * a0;
                acc1v[sy] += wv2 * a1;
                acc2v[sy] += wv2 * a2;
            }
        }
    }

    // cross-half (lane ^ 32) register reduction: 16 shuffles, no LDS/barrier
    #pragma unroll
    for (int sy = 0; sy < 2; ++sy) {
        sumwv[sy].x += __shfl_xor(sumwv[sy].x, 32);
        sumwv[sy].y += __shfl_xor(sumwv[sy].y, 32);
        acc0v[sy].x += __shfl_xor(acc0v[sy].x, 32);
        acc0v[sy].y += __shfl_xor(acc0v[sy].y, 32);
        acc1v[sy].x += __shfl_xor(acc1v[sy].x, 32);
        acc1v[sy].y += __shfl_xor(acc1v[sy].y, 32);
        acc2v[sy].x += __shfl_xor(acc2v[sy].x, 32);
        acc2v[sy].y += __shfl_xor(acc2v[sy].y, 32);
    }

    if (fhalf == 0) {
        v2f inv[2];
        #pragma unroll
        for (int sy = 0; sy < 2; ++sy)
            inv[sy] = (v2f){1.0f / sumwv[sy].x, 1.0f / sumwv[sy].y};

        const size_t ob = (size_t)(nn * CH) * SHW + (size_t)(2 * y0) * SW + 2 * x0;
        #pragma unroll
        for (int sy = 0; sy < 2; ++sy) {
            const v2f r0 = acc0v[sy] * inv[sy];
            const v2f r1 = acc1v[sy] * inv[sy];
            const v2f r2 = acc2v[sy] * inv[sy];
            *(float2*)(out + ob + (size_t)sy * SW)           = make_float2(r0.x, r0.y);
            *(float2*)(out + ob + (size_t)sy * SW + SHW)     = make_float2(r1.x, r1.y);
            *(float2*)(out + ob + (size_t)sy * SW + 2*SHW)   = make_float2(r2.x, r2.y);
        }
    }
}

extern "C" void kernel_launch(void* const* d_in, const int* in_sizes, int n_in,
                              void* d_out, int out_size, void* d_ws, size_t ws_size,
                              hipStream_t stream) {
    const float* alts    = (const float*)d_in[0];
    const float* offsets = (const float*)d_in[1];
    const float* qs      = (const float*)d_in[2];
    const float* o11     = (const float*)d_in[3];
    const float* o12     = (const float*)d_in[4];
    const float* o21     = (const float*)d_in[5];
    const float* o22     = (const float*)d_in[6];
    float* out = (float*)d_out;

    const int total_threads = NB * H * W * 2;   // 524,288 (2 frame-halves/pixel)
    const int block = 256;
    const int grid  = total_threads / block;    // 2048
    superresolve_kernel<<<grid, block, 0, stream>>>(alts, offsets, qs,
                                                    o11, o12, o21, o22, out);
}

// Round 6
// 26.010 us; speedup vs baseline: 1.4853x; 1.2172x over previous
//
#include <hip/hip_runtime.h>

// SuperResolve: A=4 frames, n=4, c=3, h=w=256, S=2 -> out (4,3,512,512) fp32
// Block = 256 thr = 4 waves over 128 LR pixels (half row, y0 uniform):
//   waves 0,1: frames {0,1};  waves 2,3: frames {2,3}  -> `a` wave-uniform.
// readfirstlane(a,nn,y0) => all plane bases in SGPRs; gathers are
// saddr + one of 3 per-thread voffsets (+imm row offset). Address VALU ~0.
// Radius masks: offsets clipped to [-1,1] => only (di=-1,sy=1) and
// (dj=-1,sx=1) can fail the RADIUS test; row bounds are scalar branches,
// col bounds are 2 precomputed lane masks. Straight-line loop bodies.
// Cross-wave reduce via LDS (stride 17, conflict-free), one barrier.
// R3 lesson: no waves/EU cap (VGPR=32 => 27MB spills). R4: need >=2048 blocks.

#define AF      4
#define NB      4
#define CH      3
#define H       256
#define W       256
#define SH      512
#define SW      512
#define HW      (H*W)
#define SHW     (SH*SW)
#define RADIUS  4.0f
// 0.25 (LR displacement scaling) * 0.5*log2(e): weight = exp2(-dist')
#define MSCALE  0.18033688011112042f
// clamp-hi: 20 * 0.5*log2(e)
#define CLHI    14.426950408889634f

typedef float v2f __attribute__((ext_vector_type(2)));

__global__ __launch_bounds__(256) void superresolve_kernel(
    const float* __restrict__ alts,     // [AF][NB][CH][H][W]
    const float* __restrict__ offsets,  // [AF][NB][2][H][W]
    const float* __restrict__ qs,       // [AF][NB][H][W]
    const float* __restrict__ o11,      // [NB][SH][SW]
    const float* __restrict__ o12,
    const float* __restrict__ o21,
    const float* __restrict__ o22,
    float* __restrict__ out)            // [NB][CH][SH][SW]
{
    __shared__ float red[128 * 17];     // 8704 B; stride 17 words: conflict-free

    const int tid   = threadIdx.x;
    const int wv    = tid >> 6;
    const int lane  = tid & 63;
    const int fpair = wv >> 1;                  // 0: frames {0,1}; 1: {2,3}
    const int pix   = ((wv & 1) << 6) + lane;   // 0..127 within block

    // bijective XCD swizzle over 2048 blocks
    const int bid = blockIdx.x;
    const int swz = (bid & 7) * 256 + (bid >> 3);
    const int P   = swz * 128 + pix;            // linear LR pixel id

    const int x0 = P & (W - 1);
    // wave-uniform values -> SGPRs
    const int y0  = __builtin_amdgcn_readfirstlane((P >> 8) & (H - 1));
    const int nn  = __builtin_amdgcn_readfirstlane(P >> 16);
    const int af0 = __builtin_amdgcn_readfirstlane(fpair << 1);

    // clamped column element-indices (the only per-lane load offsets)
    const int xL = (x0 > 0) ? x0 - 1 : 0;
    const int xR = (x0 < W - 1) ? x0 + 1 : W - 1;
    const int iL = y0 * W + xL;
    const int iC = y0 * W + x0;
    const int iR = y0 * W + xR;
    const bool bL = (x0 > 0);
    const bool bR = (x0 < W - 1);
    const float f2xL = (float)(2 * xL);
    const float f2xC = (float)(2 * x0);
    const float f2xR = (float)(2 * xR);
    const float xf0  = f2xC;
    const float yf0  = (float)(2 * y0);
    const float INF  = __builtin_inff();

    // per-subpixel o-matrices as sx-pairs (indexed by sy)
    const int obase = (nn * SH + 2 * y0) * SW + 2 * x0;
    const float2 v11a = *(const float2*)(o11 + obase);
    const float2 v11b = *(const float2*)(o11 + obase + SW);
    const float2 v12a = *(const float2*)(o12 + obase);
    const float2 v12b = *(const float2*)(o12 + obase + SW);
    const float2 v21a = *(const float2*)(o21 + obase);
    const float2 v21b = *(const float2*)(o21 + obase + SW);
    const float2 v22a = *(const float2*)(o22 + obase);
    const float2 v22b = *(const float2*)(o22 + obase + SW);

    v2f m11v[2], m12v[2], m22v[2];
    m11v[0] = (v2f){MSCALE * v11a.x, MSCALE * v11a.y};
    m11v[1] = (v2f){MSCALE * v11b.x, MSCALE * v11b.y};
    m12v[0] = (v2f){MSCALE * (v12a.x + v21a.x), MSCALE * (v12a.y + v21a.y)};
    m12v[1] = (v2f){MSCALE * (v12b.x + v21b.x), MSCALE * (v12b.y + v21b.y)};
    m22v[0] = (v2f){MSCALE * v22a.x, MSCALE * v22a.y};
    m22v[1] = (v2f){MSCALE * v22b.x, MSCALE * v22b.y};

    v2f sumwv[2] = {(v2f){0.f,0.f}, (v2f){0.f,0.f}};
    v2f acc0v[2] = {(v2f){0.f,0.f}, (v2f){0.f,0.f}};
    v2f acc1v[2] = {(v2f){0.f,0.f}, (v2f){0.f,0.f}};
    v2f acc2v[2] = {(v2f){0.f,0.f}, (v2f){0.f,0.f}};

    // COLK: one (a, row, column) contribution for all 4 subpixels.
    // COLB: compile-time-selected lane mask; IS_L/NEED_VY: compile-time flags.
#define COLK(or_, oc_, q_, a0_, a1_, a2_, f2x_, COLB, IS_L, NEED_VY)          \
    {                                                                         \
        const float posr = fmaf(or_, 2.0f, rowf);                             \
        const float dy0v = posr - yf0;                                        \
        const float dy1v = dy0v - 1.0f;                                       \
        const float posc = fmaf(oc_, 2.0f, f2x_);                             \
        const float dx0v = posc - xf0;                                        \
        const float dx1v = dx0v - 1.0f;                                       \
        const v2f dxv = (v2f){dx0v, dx1v};                                    \
        const bool vx1 = IS_L ? (dx1v >= -RADIUS) : true;                     \
        _Pragma("unroll")                                                     \
        for (int sy = 0; sy < 2; ++sy) {                                      \
            const float dyv = sy ? dy1v : dy0v;                               \
            const bool okb = (COLB) && (NEED_VY && sy ? (dy1v >= -RADIUS)     \
                                                      : true);                \
            const v2f u = dxv * m11v[sy] + dyv * m12v[sy];                    \
            v2f dv = dxv * u + (dyv * dyv) * m22v[sy];                        \
            dv = __builtin_elementwise_min(dv, (v2f){CLHI, CLHI});            \
            const float f0 = okb ? dv.x : INF;                                \
            const float f1 = (okb && vx1) ? dv.y : INF;                       \
            const v2f ev  = (v2f){exp2f(-f0), exp2f(-f1)};                    \
            const v2f wv2 = ev * (q_);                                        \
            sumwv[sy] += wv2;                                                 \
            acc0v[sy] += wv2 * (a0_);                                         \
            acc1v[sy] += wv2 * (a1_);                                         \
            acc2v[sy] += wv2 * (a2_);                                         \
        }                                                                     \
    }

    #pragma unroll
    for (int ai = 0; ai < 2; ++ai) {
        const int a = af0 + ai;   // scalar
        const float* offbR = offsets + (size_t)(a * NB + nn) * 2 * HW;
        const float* offbC = offbR + HW;
        const float* qb    = qs   + (size_t)(a * NB + nn) * HW;
        const float* ab0   = alts + (size_t)(a * NB + nn) * CH * HW;
        const float* ab1   = ab0 + HW;
        const float* ab2   = ab0 + 2 * HW;

        #pragma unroll
        for (int di = -1; di <= 1; ++di) {
            if (di == -1 && y0 == 0) continue;       // scalar uniform skip
            if (di == +1 && y0 == H - 1) continue;
            const int ro = di * W;                   // scalar row offset
            const float* pR = offbR + ro;
            const float* pC = offbC + ro;
            const float* pQ = qb + ro;
            const float* p0 = ab0 + ro;
            const float* p1 = ab1 + ro;
            const float* p2 = ab2 + ro;
            const float rowf = (float)(2 * (y0 + di));

            // 18 batched gathers (saddr + {iL,iC,iR})
            const float orL = pR[iL], orC = pR[iC], orR = pR[iR];
            const float ocL = pC[iL], ocC = pC[iC], ocR = pC[iR];
            const float qL  = pQ[iL], qC  = pQ[iC], qR  = pQ[iR];
            const float aL0 = p0[iL], aC0 = p0[iC], aR0 = p0[iR];
            const float aL1 = p1[iL], aC1 = p1[iC], aR1 = p1[iR];
            const float aL2 = p2[iL], aC2 = p2[iC], aR2 = p2[iR];

            const bool needvy = (di == -1);
            COLK(orL, ocL, qL, aL0, aL1, aL2, f2xL, bL,   true,  needvy)
            COLK(orC, ocC, qC, aC0, aC1, aC2, f2xC, true, false, needvy)
            COLK(orR, ocR, qR, aR0, aR1, aR2, f2xR, bR,   false, needvy)
        }
    }
#undef COLK

    // cross-wave reduction: fpair 1 writes 16 floats/pixel, fpair 0 sums+stores
    if (fpair == 1) {
        float* r = &red[pix * 17];
        #pragma unroll
        for (int sy = 0; sy < 2; ++sy) {
            r[sy*8+0] = sumwv[sy].x; r[sy*8+1] = sumwv[sy].y;
            r[sy*8+2] = acc0v[sy].x; r[sy*8+3] = acc0v[sy].y;
            r[sy*8+4] = acc1v[sy].x; r[sy*8+5] = acc1v[sy].y;
            r[sy*8+6] = acc2v[sy].x; r[sy*8+7] = acc2v[sy].y;
        }
    }
    __syncthreads();
    if (fpair == 0) {
        const float* r = &red[pix * 17];
        #pragma unroll
        for (int sy = 0; sy < 2; ++sy) {
            sumwv[sy].x += r[sy*8+0]; sumwv[sy].y += r[sy*8+1];
            acc0v[sy].x += r[sy*8+2]; acc0v[sy].y += r[sy*8+3];
            acc1v[sy].x += r[sy*8+4]; acc1v[sy].y += r[sy*8+5];
            acc2v[sy].x += r[sy*8+6]; acc2v[sy].y += r[sy*8+7];
        }
        const size_t ob = (size_t)(nn * CH) * SHW + (size_t)(2 * y0) * SW + 2 * x0;
        #pragma unroll
        for (int sy = 0; sy < 2; ++sy) {
            const v2f inv = (v2f){1.0f / sumwv[sy].x, 1.0f / sumwv[sy].y};
            const v2f r0 = acc0v[sy] * inv;
            const v2f r1 = acc1v[sy] * inv;
            const v2f r2 = acc2v[sy] * inv;
            *(float2*)(out + ob + (size_t)sy * SW)         = make_float2(r0.x, r0.y);
            *(float2*)(out + ob + (size_t)sy * SW + SHW)   = make_float2(r1.x, r1.y);
            *(float2*)(out + ob + (size_t)sy * SW + 2*SHW) = make_float2(r2.x, r2.y);
        }
    }
}

extern "C" void kernel_launch(void* const* d_in, const int* in_sizes, int n_in,
                              void* d_out, int out_size, void* d_ws, size_t ws_size,
                              hipStream_t stream) {
    const float* alts    = (const float*)d_in[0];
    const float* offsets = (const float*)d_in[1];
    const float* qs      = (const float*)d_in[2];
    const float* o11     = (const float*)d_in[3];
    const float* o12     = (const float*)d_in[4];
    const float* o21     = (const float*)d_in[5];
    const float* o22     = (const float*)d_in[6];
    float* out = (float*)d_out;

    const int total_threads = NB * H * W * 2;   // 524,288
    const int block = 256;
    const int grid  = total_threads / block;    // 2048
    superresolve_kernel<<<grid, block, 0, stream>>>(alts, offsets, qs,
                                                    o11, o12, o21, o22, out);
}